// Round 20
// baseline (1974.434 us; speedup 1.0000x reference)
//
#include <hip/hip_runtime.h>
#include <math.h>

#define HID 64
#define NCLS 20
#define EPS_CLS 1e-5f
#define EPS_AL 1e-6f
#define NCMAX 10240
#define MAXMARK 192
#define QPB 64      // queries per scan block
#define NCHUNK 4    // candidate chunks per query

__device__ __forceinline__ float relu_(float x){ return x > 0.f ? x : 0.f; }

__device__ __forceinline__ float pin(float v){
  asm volatile("" : "+v"(v));
  return v;
}
__device__ __forceinline__ float mulrn_b(float a, float b){ return pin(__fmul_rn(a,b)); }
__device__ __forceinline__ float addrn_b(float a, float b){ return pin(__fadd_rn(a,b)); }
__device__ __forceinline__ float subrn_b(float a, float b){ return pin(__fsub_rn(a,b)); }

__device__ __forceinline__ float np_norm2(float x, float y, float z){
  return addrn_b(addrn_b(mulrn_b(x,x), mulrn_b(y,y)), mulrn_b(z,z));
}

// exact numpy-twin lattice d2 (verified R18/R19)
__device__ __forceinline__ float lattice_d2(float qx, float qy, float qz, float n2,
                                            float cx, float cy, float cz, float m2){
  float p0  = mulrn_b(qx, cx);
  float dot = pin(fmaf(qz, cz, fmaf(qy, cy, p0)));
  float nm  = addrn_b(n2, m2);
  float t2d = mulrn_b(2.0f, dot);
  return subrn_b(nm, t2d);
}

// ---------------- Kernel A: conv_cls head (unchanged, passes) ----------------
__global__ void __launch_bounds__(64) cls_head_kernel(
    const float* __restrict__ feats, const float* __restrict__ w1,
    const float* __restrict__ bn_g, const float* __restrict__ bn_b,
    const float* __restrict__ bn_m, const float* __restrict__ bn_v,
    const float* __restrict__ w2, const float* __restrict__ b2,
    float* __restrict__ out, int R)
{
  __shared__ float s1[HID], t1[HID];
  int tx = threadIdx.x;
  if (tx < HID) {
    float s = bn_g[tx] / sqrtf(bn_v[tx] + EPS_CLS);
    s1[tx] = s;
    t1[tx] = bn_b[tx] - bn_m[tx] * s;
  }
  __syncthreads();
  int r = blockIdx.x * 64 + tx;
  if (r >= R) return;
  float x[HID];
  const float4* xr = (const float4*)(feats + (size_t)r * HID);
  #pragma unroll
  for (int i = 0; i < 16; i++) {
    float4 t = xr[i];
    x[4*i+0]=t.x; x[4*i+1]=t.y; x[4*i+2]=t.z; x[4*i+3]=t.w;
  }
  float o[NCLS];
  #pragma unroll
  for (int c = 0; c < NCLS; c++) o[c] = b2[c];
  #pragma unroll
  for (int j = 0; j < HID; j++) {
    float acc = 0.f;
    #pragma unroll
    for (int k = 0; k < HID; k++) acc = fmaf(x[k], w1[k*HID + j], acc);
    float h = relu_(acc * s1[j] + t1[j]);
    #pragma unroll
    for (int c = 0; c < NCLS; c++) o[c] = fmaf(h, w2[j*NCLS + c], o[c]);
  }
  float4* op = (float4*)(out + (size_t)r * NCLS);
  #pragma unroll
  for (int i = 0; i < 5; i++) op[i] = make_float4(o[4*i], o[4*i+1], o[4*i+2], o[4*i+3]);
}

// ---------------- Kernel B1: chunked 3-NN scan + in-block merge + tie mark ----------------
__global__ void __launch_bounds__(256) knn_scan_kernel(
    const float4* __restrict__ coords, const float4* __restrict__ pts,
    float* __restrict__ wd, int* __restrict__ wi,
    int* __restrict__ mark_cnt, int* __restrict__ mark_rows,
    int NC, int NP)
{
  __shared__ float sd[QPB][NCHUNK][4];
  __shared__ int   si[QPB][NCHUNK][4];
  int frame = blockIdx.z;
  int tx    = threadIdx.x;
  int qid   = tx & (QPB - 1);
  int chunk = tx >> 6;
  int q = blockIdx.x * QPB + qid;
  bool valid = (q < NP);

  float qx=0.f, qy=0.f, qz=0.f, n2=0.f;
  if (valid) {
    float4 p = pts[(size_t)frame * NP + q];
    qx=p.y; qy=p.z; qz=p.w;
    n2 = np_norm2(qx,qy,qz);
  }
  int clen = (NC + NCHUNK - 1) / NCHUNK;
  int c0 = chunk * clen, c1 = min(NC, c0 + clen);
  float d0=1e30f, d1=1e30f, d2v=1e30f, d3=1e30f;
  int   i0=0, i1=0, i2=0, i3=0;
  const float4* C = coords + (size_t)frame * NC;
  for (int j = c0; j < c1; j++) {
    float4 c = C[j];                       // wave-uniform -> broadcast
    float m2 = np_norm2(c.y, c.z, c.w);
    float dd = lattice_d2(qx,qy,qz,n2, c.y,c.z,c.w,m2);
    if (dd < d3) {
      if (dd < d1) {
        if (dd < d0) { d3=d2v;i3=i2; d2v=d1;i2=i1; d1=d0;i1=i0; d0=dd;i0=j; }
        else         { d3=d2v;i3=i2; d2v=d1;i2=i1; d1=dd;i1=j; }
      } else {
        if (dd < d2v){ d3=d2v;i3=i2; d2v=dd;i2=j; }
        else         { d3=dd; i3=j; }
      }
    }
  }
  sd[qid][chunk][0]=d0; sd[qid][chunk][1]=d1; sd[qid][chunk][2]=d2v; sd[qid][chunk][3]=d3;
  si[qid][chunk][0]=i0; si[qid][chunk][1]=i1; si[qid][chunk][2]=i2; si[qid][chunk][3]=i3;
  __syncthreads();
  if (tx < QPB && valid) {
    float m0=1e30f, m1=1e30f, m2v=1e30f, m3=1e30f;
    int   j0=0, j1=0, j2=0;
    #pragma unroll
    for (int c = 0; c < NCHUNK; c++) {
      #pragma unroll
      for (int r = 0; r < 4; r++) {
        float dd = sd[tx][c][r]; int jj = si[tx][c][r];
        if (dd < m3) {
          if (dd < m1) {
            if (dd < m0) { m3=m2v; m2v=m1;j2=j1; m1=m0;j1=j0; m0=dd;j0=jj; }
            else         { m3=m2v; m2v=m1;j2=j1; m1=dd;j1=jj; }
          } else {
            if (dd < m2v){ m3=m2v; m2v=dd;j2=jj; }
            else         { m3=dd; }
          }
        }
      }
    }
    int row = frame * NP + q;
    size_t base = (size_t)row * 3;
    wd[base+0]=m0; wd[base+1]=m1; wd[base+2]=m2v;
    wi[base+0]=j0; wi[base+1]=j1; wi[base+2]=j2;
    if (m2v == m3) {                   // exact lattice tie at the set boundary
      int slot = atomicAdd(mark_cnt, 1);
      if (slot < MAXMARK) mark_rows[slot] = row;
    }
  }
}

// ---------------- numpy aquicksort head, 8-wide chunked scans ----------------
// Identical swap/stop semantics to numpy's aquicksort (pruned to positions 0..3);
// scans load 8 elements per latency instead of 1 (stop position unchanged:
// first element failing the strict-< test, tested in order).
#define QSW(i,j) { float fv=v[i]; v[i]=v[j]; v[j]=fv; unsigned short uv=t[i]; t[i]=t[j]; t[j]=uv; }

__device__ __forceinline__ int scanL(const float* v, int i, float vp, float& val){
  for (;;) {
    float a0=v[i],a1=v[i+1],a2=v[i+2],a3=v[i+3],a4=v[i+4],a5=v[i+5],a6=v[i+6],a7=v[i+7];
    if (!(a0 < vp)) { val=a0; return i;   }
    if (!(a1 < vp)) { val=a1; return i+1; }
    if (!(a2 < vp)) { val=a2; return i+2; }
    if (!(a3 < vp)) { val=a3; return i+3; }
    if (!(a4 < vp)) { val=a4; return i+4; }
    if (!(a5 < vp)) { val=a5; return i+5; }
    if (!(a6 < vp)) { val=a6; return i+6; }
    if (!(a7 < vp)) { val=a7; return i+7; }
    i += 8;
  }
}
__device__ __forceinline__ int scanR(const float* v, int j, float vp, float& val){
  for (;;) {
    float a0=v[j],a1=v[j-1],a2=v[j-2],a3=v[j-3],a4=v[j-4],a5=v[j-5],a6=v[j-6],a7=v[j-7];
    if (!(vp < a0)) { val=a0; return j;   }
    if (!(vp < a1)) { val=a1; return j-1; }
    if (!(vp < a2)) { val=a2; return j-2; }
    if (!(vp < a3)) { val=a3; return j-3; }
    if (!(vp < a4)) { val=a4; return j-4; }
    if (!(vp < a5)) { val=a5; return j-5; }
    if (!(vp < a6)) { val=a6; return j-6; }
    if (!(vp < a7)) { val=a7; return j-7; }
    j -= 8;
  }
}

__device__ void np_aquicksort_head(float* v, unsigned short* t, int num)
{
  int slo[110], shi[110];
  int sp = 0;
  int pl = 0, pr = num - 1;
  for (;;) {
    bool doins = true;
    while (pr - pl > 15) {
      int pm = pl + ((pr - pl) >> 1);
      if (v[pm] < v[pl]) QSW(pm, pl);
      if (v[pr] < v[pm]) QSW(pr, pm);
      if (v[pm] < v[pl]) QSW(pm, pl);
      float vp = v[pm];
      int pi = pl, pj = pr - 1;
      QSW(pm, pj);
      for (;;) {
        float vl, vr;
        pi = scanL(v, pi + 1, vp, vl);
        pj = scanR(v, pj - 1, vp, vr);
        if (pi >= pj) break;
        v[pi] = vr; v[pj] = vl;
        unsigned short tt = t[pi]; t[pi] = t[pj]; t[pj] = tt;
      }
      QSW(pi, pr - 1);
      if (pi - pl < pr - pi) {
        if (pi + 1 <= 3) { slo[sp]=pi+1; shi[sp]=pr; sp++; }  // prune right push
        pr = pi - 1;
      } else {
        slo[sp]=pl; shi[sp]=pi-1; sp++;                       // lo=pl<=3 always
        pl = pi + 1;
        if (pl > 3) { doins = false; break; }                  // prune continue
      }
    }
    if (doins) {
      for (int a = pl + 1; a <= pr; ++a) {
        unsigned short vi = t[a]; float vv = v[a];
        int b = a;
        while (b > pl && vv < v[b-1]) { t[b]=t[b-1]; v[b]=v[b-1]; --b; }
        t[b] = vi; v[b] = vv;
      }
    }
    if (sp == 0) break;
    --sp; pl = slo[sp]; pr = shi[sp];
  }
}

// ---------------- Kernel B1.5: re-resolve tie rows via np.argsort(d2)[:, :3] ----------------
__global__ void __launch_bounds__(256) tie_resort_kernel(
    const float4* __restrict__ coords, const float4* __restrict__ pts,
    const int* __restrict__ mark_cnt, const int* __restrict__ mark_rows,
    float* __restrict__ wd, int* __restrict__ wi, int NC, int NP)
{
  // +16 pad on both sides: chunked scans may over-READ up to 7 past a stop
  __shared__ float vbuf[NCMAX + 32];
  __shared__ unsigned short tosort[NCMAX];
  float* vperm = vbuf + 16;
  int cnt = *mark_cnt; if (cnt > MAXMARK) cnt = MAXMARK;
  int b = blockIdx.x;
  if (b >= cnt) return;
  int row = mark_rows[b];
  int frame = row / NP;
  int q = row - frame * NP;
  float4 p = pts[(size_t)frame * NP + q];
  float qx=p.y, qy=p.z, qz=p.w;
  float n2 = np_norm2(qx,qy,qz);
  const float4* C = coords + (size_t)frame * NC;
  for (int i = threadIdx.x; i < NC; i += 256) {
    float4 cr = C[i];
    float m2 = np_norm2(cr.y, cr.z, cr.w);
    vperm[i]  = lattice_d2(qx,qy,qz,n2, cr.y,cr.z,cr.w,m2);
    tosort[i] = (unsigned short)i;
  }
  __syncthreads();
  if (threadIdx.x == 0) {
    np_aquicksort_head(vperm, tosort, NC);
    size_t base = (size_t)row * 3;
    wd[base+0]=vperm[0];  wd[base+1]=vperm[1];  wd[base+2]=vperm[2];
    wi[base+0]=tosort[0]; wi[base+1]=tosort[1]; wi[base+2]=tosort[2];
  }
}

// ---------------- Kernel B2: np-f32 weights + interpolate + align + out head ----------------
__global__ void __launch_bounds__(64) interp_mlp_kernel(
    const float* __restrict__ feats,
    const float* __restrict__ wd, const int* __restrict__ wi,
    const float* __restrict__ al_w, const float* __restrict__ al_b,
    const float* __restrict__ al_g, const float* __restrict__ al_bb,
    const float* __restrict__ al_m, const float* __restrict__ al_v,
    const float* __restrict__ o_w1,
    const float* __restrict__ o_g, const float* __restrict__ o_bb,
    const float* __restrict__ o_m, const float* __restrict__ o_v,
    const float* __restrict__ o_w2, const float* __restrict__ o_b2,
    float* __restrict__ out, int NC, int NP, int B)
{
  __shared__ float s1[HID], t1[HID], s2[HID], t2[HID];
  int tx = threadIdx.x;
  if (tx < HID) {
    float sa = al_g[tx] / sqrtf(al_v[tx] + EPS_AL);
    s1[tx] = sa;
    t1[tx] = (al_b[tx] - al_m[tx]) * sa + al_bb[tx];
    float so = o_g[tx] / sqrtf(o_v[tx] + EPS_CLS);
    s2[tx] = so;
    t2[tx] = o_bb[tx] - o_m[tx] * so;
  }
  __syncthreads();
  int r = blockIdx.x * 64 + tx;
  if (r >= B * NP) return;
  int frame = r / NP;

  float bd0 = wd[(size_t)r*3+0], bd1 = wd[(size_t)r*3+1], bd2 = wd[(size_t)r*3+2];
  int   bi0 = wi[(size_t)r*3+0], bi1 = wi[(size_t)r*3+1], bi2 = wi[(size_t)r*3+2];

  float w0 = pin(__fdiv_rn(1.0f, addrn_b(fmaxf(bd0, 0.f), 1e-8f)));
  float w1 = pin(__fdiv_rn(1.0f, addrn_b(fmaxf(bd1, 0.f), 1e-8f)));
  float w2 = pin(__fdiv_rn(1.0f, addrn_b(fmaxf(bd2, 0.f), 1e-8f)));
  float wsum = addrn_b(addrn_b(w0, w1), w2);
  w0 = pin(__fdiv_rn(w0, wsum)); w1 = pin(__fdiv_rn(w1, wsum)); w2 = pin(__fdiv_rn(w2, wsum));

  const float* F = feats + (size_t)frame * NC * HID;
  const float4* F0 = (const float4*)(F + (size_t)bi0 * HID);
  const float4* F1 = (const float4*)(F + (size_t)bi1 * HID);
  const float4* F2 = (const float4*)(F + (size_t)bi2 * HID);

  float interp[HID];
  #pragma unroll
  for (int i = 0; i < 16; i++) {
    float4 a = F0[i], b = F1[i], c = F2[i];
    interp[4*i+0] = (a.x*w0 + b.x*w1) + c.x*w2;
    interp[4*i+1] = (a.y*w0 + b.y*w1) + c.y*w2;
    interp[4*i+2] = (a.z*w0 + b.z*w1) + c.z*w2;
    interp[4*i+3] = (a.w*w0 + b.w*w1) + c.w*w2;
  }

  float f[HID];
  #pragma unroll
  for (int j = 0; j < HID; j++) {
    float acc = 0.f;
    #pragma unroll
    for (int k = 0; k < HID; k++) acc = fmaf(interp[k], al_w[k*HID + j], acc);
    f[j] = relu_(acc * s1[j] + t1[j]);
  }
  float o[NCLS];
  #pragma unroll
  for (int c = 0; c < NCLS; c++) o[c] = o_b2[c];
  #pragma unroll
  for (int j = 0; j < HID; j++) {
    float acc = 0.f;
    #pragma unroll
    for (int k = 0; k < HID; k++) acc = fmaf(f[k], o_w1[k*HID + j], acc);
    float h = relu_(acc * s2[j] + t2[j]);
    #pragma unroll
    for (int c = 0; c < NCLS; c++) o[c] = fmaf(h, o_w2[j*NCLS + c], o[c]);
  }
  float4* op = (float4*)(out + (size_t)r * NCLS);
  #pragma unroll
  for (int i = 0; i < 5; i++) op[i] = make_float4(o[4*i], o[4*i+1], o[4*i+2], o[4*i+3]);
}

extern "C" void kernel_launch(void* const* d_in, const int* in_sizes, int n_in,
                              void* d_out, int out_size, void* d_ws, size_t ws_size,
                              hipStream_t stream)
{
  const float*  feats  = (const float*) d_in[0];
  const float4* coords = (const float4*)d_in[1];
  const float4* pts    = (const float4*)d_in[2];
  const float* cls_w1 = (const float*)d_in[3];
  const float* cls_g  = (const float*)d_in[4];
  const float* cls_b  = (const float*)d_in[5];
  const float* cls_m  = (const float*)d_in[6];
  const float* cls_v  = (const float*)d_in[7];
  const float* cls_w2 = (const float*)d_in[8];
  const float* cls_b2 = (const float*)d_in[9];
  const float* al_w   = (const float*)d_in[10];
  const float* al_b   = (const float*)d_in[11];
  const float* al_g   = (const float*)d_in[12];
  const float* al_bb  = (const float*)d_in[13];
  const float* al_m   = (const float*)d_in[14];
  const float* al_v   = (const float*)d_in[15];
  const float* o_w1   = (const float*)d_in[16];
  const float* o_g    = (const float*)d_in[17];
  const float* o_bb   = (const float*)d_in[18];
  const float* o_m    = (const float*)d_in[19];
  const float* o_v    = (const float*)d_in[20];
  const float* o_w2   = (const float*)d_in[21];
  const float* o_b2   = (const float*)d_in[22];

  const int B = 2;
  int RC = in_sizes[1] / 4;  int NC = RC / B;
  int RP = in_sizes[2] / 4;  int NP = RP / B;

  int*   mark_cnt  = (int*)d_ws;
  int*   mark_rows = (int*)((char*)d_ws + 16);
  float* wd = (float*)((char*)d_ws + 16 + 4*MAXMARK);
  int*   wi = (int*)((char*)wd + (size_t)RP * 3 * 4);

  hipMemsetAsync(d_ws, 0, 16, stream);

  cls_head_kernel<<<(RC + 63) / 64, 64, 0, stream>>>(
      feats, cls_w1, cls_g, cls_b, cls_m, cls_v, cls_w2, cls_b2,
      (float*)d_out, RC);

  dim3 g1((NP + QPB - 1) / QPB, 1, B);
  knn_scan_kernel<<<g1, 256, 0, stream>>>(coords, pts, wd, wi,
                                          mark_cnt, mark_rows, NC, NP);

  tie_resort_kernel<<<MAXMARK, 256, 0, stream>>>(coords, pts, mark_cnt, mark_rows,
                                                 wd, wi, NC, NP);

  float* out2 = (float*)d_out + (size_t)RC * NCLS;
  interp_mlp_kernel<<<(RP + 63) / 64, 64, 0, stream>>>(
      feats, wd, wi,
      al_w, al_b, al_g, al_bb, al_m, al_v,
      o_w1, o_g, o_bb, o_m, o_v, o_w2, o_b2,
      out2, NC, NP, B);
}

// Round 21
// 658.173 us; speedup vs baseline: 2.9999x; 2.9999x over previous
//
#include <hip/hip_runtime.h>
#include <math.h>

#define HID 64
#define NCLS 20
#define EPS_CLS 1e-5f
#define EPS_AL 1e-6f
#define NCMAX 10240
#define NWORDS ((NCMAX + 31) / 32 + 1)
#define MAXMARK 192
#define QPB 64      // queries per scan block
#define NCHUNK 4    // candidate chunks per query

__device__ __forceinline__ float relu_(float x){ return x > 0.f ? x : 0.f; }

__device__ __forceinline__ float pin(float v){
  asm volatile("" : "+v"(v));
  return v;
}
__device__ __forceinline__ float mulrn_b(float a, float b){ return pin(__fmul_rn(a,b)); }
__device__ __forceinline__ float addrn_b(float a, float b){ return pin(__fadd_rn(a,b)); }
__device__ __forceinline__ float subrn_b(float a, float b){ return pin(__fsub_rn(a,b)); }

__device__ __forceinline__ float np_norm2(float x, float y, float z){
  return addrn_b(addrn_b(mulrn_b(x,x), mulrn_b(y,y)), mulrn_b(z,z));
}

// exact numpy-twin lattice d2 (verified R18/R19)
__device__ __forceinline__ float lattice_d2(float qx, float qy, float qz, float n2,
                                            float cx, float cy, float cz, float m2){
  float p0  = mulrn_b(qx, cx);
  float dot = pin(fmaf(qz, cz, fmaf(qy, cy, p0)));
  float nm  = addrn_b(n2, m2);
  float t2d = mulrn_b(2.0f, dot);
  return subrn_b(nm, t2d);
}

// ---------------- Kernel A: conv_cls head (unchanged, passes) ----------------
__global__ void __launch_bounds__(64) cls_head_kernel(
    const float* __restrict__ feats, const float* __restrict__ w1,
    const float* __restrict__ bn_g, const float* __restrict__ bn_b,
    const float* __restrict__ bn_m, const float* __restrict__ bn_v,
    const float* __restrict__ w2, const float* __restrict__ b2,
    float* __restrict__ out, int R)
{
  __shared__ float s1[HID], t1[HID];
  int tx = threadIdx.x;
  if (tx < HID) {
    float s = bn_g[tx] / sqrtf(bn_v[tx] + EPS_CLS);
    s1[tx] = s;
    t1[tx] = bn_b[tx] - bn_m[tx] * s;
  }
  __syncthreads();
  int r = blockIdx.x * 64 + tx;
  if (r >= R) return;
  float x[HID];
  const float4* xr = (const float4*)(feats + (size_t)r * HID);
  #pragma unroll
  for (int i = 0; i < 16; i++) {
    float4 t = xr[i];
    x[4*i+0]=t.x; x[4*i+1]=t.y; x[4*i+2]=t.z; x[4*i+3]=t.w;
  }
  float o[NCLS];
  #pragma unroll
  for (int c = 0; c < NCLS; c++) o[c] = b2[c];
  #pragma unroll
  for (int j = 0; j < HID; j++) {
    float acc = 0.f;
    #pragma unroll
    for (int k = 0; k < HID; k++) acc = fmaf(x[k], w1[k*HID + j], acc);
    float h = relu_(acc * s1[j] + t1[j]);
    #pragma unroll
    for (int c = 0; c < NCLS; c++) o[c] = fmaf(h, w2[j*NCLS + c], o[c]);
  }
  float4* op = (float4*)(out + (size_t)r * NCLS);
  #pragma unroll
  for (int i = 0; i < 5; i++) op[i] = make_float4(o[4*i], o[4*i+1], o[4*i+2], o[4*i+3]);
}

// ---------------- Kernel B1: chunked 3-NN scan + in-block merge + tie mark ----------------
__global__ void __launch_bounds__(256) knn_scan_kernel(
    const float4* __restrict__ coords, const float4* __restrict__ pts,
    float* __restrict__ wd, int* __restrict__ wi,
    int* __restrict__ mark_cnt, int* __restrict__ mark_rows,
    int NC, int NP)
{
  __shared__ float sd[QPB][NCHUNK][4];
  __shared__ int   si[QPB][NCHUNK][4];
  int frame = blockIdx.z;
  int tx    = threadIdx.x;
  int qid   = tx & (QPB - 1);
  int chunk = tx >> 6;
  int q = blockIdx.x * QPB + qid;
  bool valid = (q < NP);

  float qx=0.f, qy=0.f, qz=0.f, n2=0.f;
  if (valid) {
    float4 p = pts[(size_t)frame * NP + q];
    qx=p.y; qy=p.z; qz=p.w;
    n2 = np_norm2(qx,qy,qz);
  }
  int clen = (NC + NCHUNK - 1) / NCHUNK;
  int c0 = chunk * clen, c1 = min(NC, c0 + clen);
  float d0=1e30f, d1=1e30f, d2v=1e30f, d3=1e30f;
  int   i0=0, i1=0, i2=0, i3=0;
  const float4* C = coords + (size_t)frame * NC;
  for (int j = c0; j < c1; j++) {
    float4 c = C[j];                       // wave-uniform -> broadcast
    float m2 = np_norm2(c.y, c.z, c.w);
    float dd = lattice_d2(qx,qy,qz,n2, c.y,c.z,c.w,m2);
    if (dd < d3) {
      if (dd < d1) {
        if (dd < d0) { d3=d2v;i3=i2; d2v=d1;i2=i1; d1=d0;i1=i0; d0=dd;i0=j; }
        else         { d3=d2v;i3=i2; d2v=d1;i2=i1; d1=dd;i1=j; }
      } else {
        if (dd < d2v){ d3=d2v;i3=i2; d2v=dd;i2=j; }
        else         { d3=dd; i3=j; }
      }
    }
  }
  sd[qid][chunk][0]=d0; sd[qid][chunk][1]=d1; sd[qid][chunk][2]=d2v; sd[qid][chunk][3]=d3;
  si[qid][chunk][0]=i0; si[qid][chunk][1]=i1; si[qid][chunk][2]=i2; si[qid][chunk][3]=i3;
  __syncthreads();
  if (tx < QPB && valid) {
    float m0=1e30f, m1=1e30f, m2v=1e30f, m3=1e30f;
    int   j0=0, j1=0, j2=0;
    #pragma unroll
    for (int c = 0; c < NCHUNK; c++) {
      #pragma unroll
      for (int r = 0; r < 4; r++) {
        float dd = sd[tx][c][r]; int jj = si[tx][c][r];
        if (dd < m3) {
          if (dd < m1) {
            if (dd < m0) { m3=m2v; m2v=m1;j2=j1; m1=m0;j1=j0; m0=dd;j0=jj; }
            else         { m3=m2v; m2v=m1;j2=j1; m1=dd;j1=jj; }
          } else {
            if (dd < m2v){ m3=m2v; m2v=dd;j2=jj; }
            else         { m3=dd; }
          }
        }
      }
    }
    int row = frame * NP + q;
    size_t base = (size_t)row * 3;
    wd[base+0]=m0; wd[base+1]=m1; wd[base+2]=m2v;
    wi[base+0]=j0; wi[base+1]=j1; wi[base+2]=j2;
    if (m2v == m3) {                   // exact lattice tie at the set boundary
      int slot = atomicAdd(mark_cnt, 1);
      if (slot < MAXMARK) mark_rows[slot] = row;
    }
  }
}

// ---------------- Kernel B1.5: block-PARALLEL exact numpy argsort head ----------------
// Permutes only the index array t (like numpy's aquicksort for argsort); values
// are gathered via t and recomputed from coords (deterministic lattice).
// Each Hoare partition is computed in closed form:
//   L = ascending positions with !(v<vp) in [pl+1, pr-1]  (pivot sentinel at pr-1)
//   R = descending positions with !(vp<v) in [pl, pr-2]
//   K = #{k : L[k] < R[k]}   (monotone), parallel swaps of pairs (L[k],R[k]), k<K
//   pivot lands at pi = min(L[K], K>0 ? R[K-1] : INF)
// Recursion pruned to final positions 0..3 (same decisions as passing R18/R19).
__global__ void __launch_bounds__(256) tie_resort_kernel(
    const float4* __restrict__ coords, const float4* __restrict__ pts,
    const int* __restrict__ mark_cnt, const int* __restrict__ mark_rows,
    float* __restrict__ wd, int* __restrict__ wi, int NC, int NP)
{
  __shared__ unsigned short t[NCMAX];
  __shared__ unsigned short Rpos[NCMAX];
  __shared__ unsigned int abit[NWORDS], bbit[NWORDS];
  __shared__ int scanA[256], scanB[256];
  __shared__ int s_pl, s_pr, s_sp, s_state, s_K, s_LK;
  __shared__ float s_vp, s_q[4], vloc[16];
  __shared__ int s_slo[64], s_shi[64];

  int cnt = *mark_cnt; if (cnt > MAXMARK) cnt = MAXMARK;
  int b = blockIdx.x;
  if (b >= cnt) return;
  int row = mark_rows[b];
  int frame = row / NP;
  int q = row - frame * NP;
  int tid = threadIdx.x;

  if (tid == 0) {
    float4 p = pts[(size_t)frame * NP + q];
    s_q[0]=p.y; s_q[1]=p.z; s_q[2]=p.w;
    s_q[3]=np_norm2(p.y,p.z,p.w);
    s_pl = 0; s_pr = NC - 1; s_sp = 0; s_state = 0;
  }
  for (int i = tid; i < NC; i += 256) t[i] = (unsigned short)i;
  __syncthreads();
  float qx=s_q[0], qy=s_q[1], qz=s_q[2], n2=s_q[3];
  const float4* C = coords + (size_t)frame * NC;

  auto V = [&](int p)->float {
    float4 c = C[t[p]];
    float m2 = np_norm2(c.y, c.z, c.w);
    return lattice_d2(qx,qy,qz,n2, c.y,c.z,c.w,m2);
  };

  for (;;) {
    __syncthreads();
    if (s_state) break;
    int pl = s_pl, pr = s_pr;

    if (pr - pl > 15) {
      // ---- med3 + park pivot (serial, tiny) ----
      if (tid == 0) {
        int pm = pl + ((pr - pl) >> 1);
        unsigned short tmp;
        if (V(pm) < V(pl)) { tmp=t[pm]; t[pm]=t[pl]; t[pl]=tmp; }
        if (V(pr) < V(pm)) { tmp=t[pr]; t[pr]=t[pm]; t[pm]=tmp; }
        if (V(pm) < V(pl)) { tmp=t[pm]; t[pm]=t[pl]; t[pl]=tmp; }
        s_vp = V(pm);
        tmp=t[pm]; t[pm]=t[pr-1]; t[pr-1]=tmp;
        s_K = 0;
      }
      __syncthreads();
      float vp = s_vp;
      int M = pr - pl + 1;
      int nwords = (M + 31) >> 5;
      int wpt = (nwords + 255) >> 8;        // words per thread (1 or 2)
      int wlo = tid * wpt;
      int whi = min(wlo + wpt, nwords);

      // ---- pass 1: predicates -> bitmaps + per-thread counts ----
      int cA = 0, cB = 0;
      for (int w = wlo; w < whi; ++w) {
        unsigned int wa = 0, wb = 0;
        int rbase = w << 5;
        #pragma unroll 8
        for (int bit = 0; bit < 32; ++bit) {
          int r = rbase + bit;
          bool in = (r < M);
          float val = V(in ? (pl + r) : pl);
          if (in && r >= 1 && r <= M-2 && !(val < vp)) wa |= (1u << bit);
          if (in && r <= M-3 && !(vp < val))           wb |= (1u << bit);
        }
        abit[w] = wa; bbit[w] = wb;
        cA += __popc(wa); cB += __popc(wb);
      }
      scanA[tid] = cA; scanB[tid] = cB;
      __syncthreads();
      // ---- block inclusive scan (Hillis-Steele) ----
      for (int off = 1; off < 256; off <<= 1) {
        int aa = (tid >= off) ? scanA[tid-off] : 0;
        int bb = (tid >= off) ? scanB[tid-off] : 0;
        __syncthreads();
        scanA[tid] += aa; scanB[tid] += bb;
        __syncthreads();
      }
      int offA = scanA[tid] - cA;
      int offB = scanB[tid] - cB;
      int nB = scanB[255];
      __syncthreads();

      // ---- pass 2: scatter R list (descending positions) ----
      int run = offB;
      for (int w = wlo; w < whi; ++w) {
        unsigned int wb = bbit[w];
        while (wb) {
          int bit = __ffs(wb) - 1; wb &= wb - 1;
          run++;
          Rpos[nB - run] = (unsigned short)(pl + (w << 5) + bit);
        }
      }
      __syncthreads();

      // ---- pass 3: count K = #{k : L[k] < R[k]} ----
      int k = offA, localK = 0;
      for (int w = wlo; w < whi; ++w) {
        unsigned int wa = abit[w];
        while (wa) {
          int bit = __ffs(wa) - 1; wa &= wa - 1;
          int pos = pl + (w << 5) + bit;
          if (k < nB && pos < (int)Rpos[k]) localK++;
          k++;
        }
      }
      if (localK) atomicAdd(&s_K, localK);
      __syncthreads();
      int K = s_K;

      // ---- pass 4: parallel pair swaps + find L[K] ----
      k = offA;
      for (int w = wlo; w < whi; ++w) {
        unsigned int wa = abit[w];
        while (wa) {
          int bit = __ffs(wa) - 1; wa &= wa - 1;
          int pos = pl + (w << 5) + bit;
          if (k < K) {
            int pp = Rpos[k];
            unsigned short tmp = t[pos]; t[pos] = t[pp]; t[pp] = tmp;
          } else if (k == K) {
            s_LK = pos;
          }
          k++;
        }
      }
      __syncthreads();

      // ---- finalize: pivot placement + pruned recursion ----
      if (tid == 0) {
        int pi = s_LK;
        if (K > 0) { int rk = Rpos[K-1]; if (rk < pi) pi = rk; }
        unsigned short tmp = t[pi]; t[pi] = t[pr-1]; t[pr-1] = tmp;
        if (pi - pl < pr - pi) {
          if (pi + 1 <= 3) { s_slo[s_sp] = pi + 1; s_shi[s_sp] = pr; s_sp++; }
          s_pr = pi - 1;
        } else {
          s_slo[s_sp] = pl; s_shi[s_sp] = pi - 1; s_sp++;
          s_pl = pi + 1;
          if (s_pl > 3) {          // abandon (lo>3 cannot affect 0..3): pop
            --s_sp; s_pl = s_slo[s_sp]; s_pr = s_shi[s_sp];
          }
        }
      }
    } else {
      // ---- insertion tail (<=16 elems) in LDS, numpy semantics ----
      if (pr > pl && tid <= pr - pl) vloc[tid] = V(pl + tid);
      __syncthreads();
      if (tid == 0) {
        for (int a2 = pl + 1; a2 <= pr; ++a2) {
          unsigned short vi = t[a2]; float vv = vloc[a2 - pl];
          int b2 = a2;
          while (b2 > pl && vv < vloc[b2-1-pl]) {
            t[b2] = t[b2-1]; vloc[b2-pl] = vloc[b2-1-pl]; --b2;
          }
          t[b2] = vi; vloc[b2-pl] = vv;
        }
        if (s_sp == 0) s_state = 1;
        else { --s_sp; s_pl = s_slo[s_sp]; s_pr = s_shi[s_sp]; }
      }
    }
  }

  __syncthreads();
  if (tid == 0) {
    size_t base = (size_t)row * 3;
    wd[base+0]=V(0); wd[base+1]=V(1); wd[base+2]=V(2);
    wi[base+0]=t[0]; wi[base+1]=t[1]; wi[base+2]=t[2];
  }
}

// ---------------- Kernel B2: np-f32 weights + interpolate + align + out head ----------------
__global__ void __launch_bounds__(64) interp_mlp_kernel(
    const float* __restrict__ feats,
    const float* __restrict__ wd, const int* __restrict__ wi,
    const float* __restrict__ al_w, const float* __restrict__ al_b,
    const float* __restrict__ al_g, const float* __restrict__ al_bb,
    const float* __restrict__ al_m, const float* __restrict__ al_v,
    const float* __restrict__ o_w1,
    const float* __restrict__ o_g, const float* __restrict__ o_bb,
    const float* __restrict__ o_m, const float* __restrict__ o_v,
    const float* __restrict__ o_w2, const float* __restrict__ o_b2,
    float* __restrict__ out, int NC, int NP, int B)
{
  __shared__ float s1[HID], t1[HID], s2[HID], t2[HID];
  int tx = threadIdx.x;
  if (tx < HID) {
    float sa = al_g[tx] / sqrtf(al_v[tx] + EPS_AL);
    s1[tx] = sa;
    t1[tx] = (al_b[tx] - al_m[tx]) * sa + al_bb[tx];
    float so = o_g[tx] / sqrtf(o_v[tx] + EPS_CLS);
    s2[tx] = so;
    t2[tx] = o_bb[tx] - o_m[tx] * so;
  }
  __syncthreads();
  int r = blockIdx.x * 64 + tx;
  if (r >= B * NP) return;
  int frame = r / NP;

  float bd0 = wd[(size_t)r*3+0], bd1 = wd[(size_t)r*3+1], bd2 = wd[(size_t)r*3+2];
  int   bi0 = wi[(size_t)r*3+0], bi1 = wi[(size_t)r*3+1], bi2 = wi[(size_t)r*3+2];

  float w0 = pin(__fdiv_rn(1.0f, addrn_b(fmaxf(bd0, 0.f), 1e-8f)));
  float w1 = pin(__fdiv_rn(1.0f, addrn_b(fmaxf(bd1, 0.f), 1e-8f)));
  float w2 = pin(__fdiv_rn(1.0f, addrn_b(fmaxf(bd2, 0.f), 1e-8f)));
  float wsum = addrn_b(addrn_b(w0, w1), w2);
  w0 = pin(__fdiv_rn(w0, wsum)); w1 = pin(__fdiv_rn(w1, wsum)); w2 = pin(__fdiv_rn(w2, wsum));

  const float* F = feats + (size_t)frame * NC * HID;
  const float4* F0 = (const float4*)(F + (size_t)bi0 * HID);
  const float4* F1 = (const float4*)(F + (size_t)bi1 * HID);
  const float4* F2 = (const float4*)(F + (size_t)bi2 * HID);

  float interp[HID];
  #pragma unroll
  for (int i = 0; i < 16; i++) {
    float4 a = F0[i], b = F1[i], c = F2[i];
    interp[4*i+0] = (a.x*w0 + b.x*w1) + c.x*w2;
    interp[4*i+1] = (a.y*w0 + b.y*w1) + c.y*w2;
    interp[4*i+2] = (a.z*w0 + b.z*w1) + c.z*w2;
    interp[4*i+3] = (a.w*w0 + b.w*w1) + c.w*w2;
  }

  float f[HID];
  #pragma unroll
  for (int j = 0; j < HID; j++) {
    float acc = 0.f;
    #pragma unroll
    for (int k = 0; k < HID; k++) acc = fmaf(interp[k], al_w[k*HID + j], acc);
    f[j] = relu_(acc * s1[j] + t1[j]);
  }
  float o[NCLS];
  #pragma unroll
  for (int c = 0; c < NCLS; c++) o[c] = o_b2[c];
  #pragma unroll
  for (int j = 0; j < HID; j++) {
    float acc = 0.f;
    #pragma unroll
    for (int k = 0; k < HID; k++) acc = fmaf(f[k], o_w1[k*HID + j], acc);
    float h = relu_(acc * s2[j] + t2[j]);
    #pragma unroll
    for (int c = 0; c < NCLS; c++) o[c] = fmaf(h, o_w2[j*NCLS + c], o[c]);
  }
  float4* op = (float4*)(out + (size_t)r * NCLS);
  #pragma unroll
  for (int i = 0; i < 5; i++) op[i] = make_float4(o[4*i], o[4*i+1], o[4*i+2], o[4*i+3]);
}

extern "C" void kernel_launch(void* const* d_in, const int* in_sizes, int n_in,
                              void* d_out, int out_size, void* d_ws, size_t ws_size,
                              hipStream_t stream)
{
  const float*  feats  = (const float*) d_in[0];
  const float4* coords = (const float4*)d_in[1];
  const float4* pts    = (const float4*)d_in[2];
  const float* cls_w1 = (const float*)d_in[3];
  const float* cls_g  = (const float*)d_in[4];
  const float* cls_b  = (const float*)d_in[5];
  const float* cls_m  = (const float*)d_in[6];
  const float* cls_v  = (const float*)d_in[7];
  const float* cls_w2 = (const float*)d_in[8];
  const float* cls_b2 = (const float*)d_in[9];
  const float* al_w   = (const float*)d_in[10];
  const float* al_b   = (const float*)d_in[11];
  const float* al_g   = (const float*)d_in[12];
  const float* al_bb  = (const float*)d_in[13];
  const float* al_m   = (const float*)d_in[14];
  const float* al_v   = (const float*)d_in[15];
  const float* o_w1   = (const float*)d_in[16];
  const float* o_g    = (const float*)d_in[17];
  const float* o_bb   = (const float*)d_in[18];
  const float* o_m    = (const float*)d_in[19];
  const float* o_v    = (const float*)d_in[20];
  const float* o_w2   = (const float*)d_in[21];
  const float* o_b2   = (const float*)d_in[22];

  const int B = 2;
  int RC = in_sizes[1] / 4;  int NC = RC / B;
  int RP = in_sizes[2] / 4;  int NP = RP / B;

  int*   mark_cnt  = (int*)d_ws;
  int*   mark_rows = (int*)((char*)d_ws + 16);
  float* wd = (float*)((char*)d_ws + 16 + 4*MAXMARK);
  int*   wi = (int*)((char*)wd + (size_t)RP * 3 * 4);

  hipMemsetAsync(d_ws, 0, 16, stream);

  cls_head_kernel<<<(RC + 63) / 64, 64, 0, stream>>>(
      feats, cls_w1, cls_g, cls_b, cls_m, cls_v, cls_w2, cls_b2,
      (float*)d_out, RC);

  dim3 g1((NP + QPB - 1) / QPB, 1, B);
  knn_scan_kernel<<<g1, 256, 0, stream>>>(coords, pts, wd, wi,
                                          mark_cnt, mark_rows, NC, NP);

  tie_resort_kernel<<<MAXMARK, 256, 0, stream>>>(coords, pts, mark_cnt, mark_rows,
                                                 wd, wi, NC, NP);

  float* out2 = (float*)d_out + (size_t)RC * NCLS;
  interp_mlp_kernel<<<(RP + 63) / 64, 64, 0, stream>>>(
      feats, wd, wi,
      al_w, al_b, al_g, al_bb, al_m, al_v,
      o_w1, o_g, o_bb, o_m, o_v, o_w2, o_b2,
      out2, NC, NP, B);
}

// Round 22
// 498.368 us; speedup vs baseline: 3.9618x; 1.3207x over previous
//
#include <hip/hip_runtime.h>
#include <math.h>

#define HID 64
#define NCLS 20
#define EPS_CLS 1e-5f
#define EPS_AL 1e-6f
#define NCMAX 10240
#define NWORDS ((NCMAX + 31) / 32 + 1)
#define MAXMARK 192
#define NSEG 8
#define STILE 512

__device__ __forceinline__ float relu_(float x){ return x > 0.f ? x : 0.f; }

__device__ __forceinline__ float pin(float v){
  asm volatile("" : "+v"(v));
  return v;
}
__device__ __forceinline__ float mulrn_b(float a, float b){ return pin(__fmul_rn(a,b)); }
__device__ __forceinline__ float addrn_b(float a, float b){ return pin(__fadd_rn(a,b)); }
__device__ __forceinline__ float subrn_b(float a, float b){ return pin(__fsub_rn(a,b)); }

__device__ __forceinline__ float np_norm2(float x, float y, float z){
  return addrn_b(addrn_b(mulrn_b(x,x), mulrn_b(y,y)), mulrn_b(z,z));
}

// exact numpy-twin lattice d2 (verified R18-R21)
__device__ __forceinline__ float lattice_d2(float qx, float qy, float qz, float n2,
                                            float cx, float cy, float cz, float m2){
  float p0  = mulrn_b(qx, cx);
  float dot = pin(fmaf(qz, cz, fmaf(qy, cy, p0)));
  float nm  = addrn_b(n2, m2);
  float t2d = mulrn_b(2.0f, dot);
  return subrn_b(nm, t2d);
}

// ---------------- Kernel A: conv_cls head (unchanged, passes) ----------------
__global__ void __launch_bounds__(64) cls_head_kernel(
    const float* __restrict__ feats, const float* __restrict__ w1,
    const float* __restrict__ bn_g, const float* __restrict__ bn_b,
    const float* __restrict__ bn_m, const float* __restrict__ bn_v,
    const float* __restrict__ w2, const float* __restrict__ b2,
    float* __restrict__ out, int R)
{
  __shared__ float s1[HID], t1[HID];
  int tx = threadIdx.x;
  if (tx < HID) {
    float s = bn_g[tx] / sqrtf(bn_v[tx] + EPS_CLS);
    s1[tx] = s;
    t1[tx] = bn_b[tx] - bn_m[tx] * s;
  }
  __syncthreads();
  int r = blockIdx.x * 64 + tx;
  if (r >= R) return;
  float x[HID];
  const float4* xr = (const float4*)(feats + (size_t)r * HID);
  #pragma unroll
  for (int i = 0; i < 16; i++) {
    float4 t = xr[i];
    x[4*i+0]=t.x; x[4*i+1]=t.y; x[4*i+2]=t.z; x[4*i+3]=t.w;
  }
  float o[NCLS];
  #pragma unroll
  for (int c = 0; c < NCLS; c++) o[c] = b2[c];
  #pragma unroll
  for (int j = 0; j < HID; j++) {
    float acc = 0.f;
    #pragma unroll
    for (int k = 0; k < HID; k++) acc = fmaf(x[k], w1[k*HID + j], acc);
    float h = relu_(acc * s1[j] + t1[j]);
    #pragma unroll
    for (int c = 0; c < NCLS; c++) o[c] = fmaf(h, w2[j*NCLS + c], o[c]);
  }
  float4* op = (float4*)(out + (size_t)r * NCLS);
  #pragma unroll
  for (int i = 0; i < 5; i++) op[i] = make_float4(o[4*i], o[4*i+1], o[4*i+2], o[4*i+3]);
}

// ---------------- Kernel B1a: segmented scan, LDS-staged m2, partial top-4 ----------------
// grid (ceil(NP/256), nseg, B); 1 query/thread; candidates of this segment staged
// in LDS tiles WITH precomputed m2 (amortized over 256 queries).
__global__ void __launch_bounds__(256) knn_scan_kernel(
    const float4* __restrict__ coords, const float4* __restrict__ pts,
    float4* __restrict__ pd, int4* __restrict__ pi,
    int NC, int NP, int nseg)
{
  __shared__ float4 tile[STILE];
  int frame = blockIdx.z;
  int seg   = blockIdx.y;
  int tid   = threadIdx.x;
  int q = blockIdx.x * 256 + tid;
  bool valid = (q < NP);

  float qx=0.f, qy=0.f, qz=0.f, n2=0.f;
  if (valid) {
    float4 p = pts[(size_t)frame * NP + q];
    qx=p.y; qy=p.z; qz=p.w;
    n2 = np_norm2(qx,qy,qz);
  }
  int SL = (NC + nseg - 1) / nseg;
  int c0 = seg * SL, c1 = min(NC, c0 + SL);
  float d0=1e30f, d1=1e30f, d2v=1e30f, d3=1e30f;
  int   i0=-1, i1=-1, i2=-1;
  const float4* C = coords + (size_t)frame * NC;

  for (int t = c0; t < c1; t += STILE) {
    int n = min(STILE, c1 - t);
    __syncthreads();
    for (int k = tid; k < n; k += 256) {
      float4 cr = C[t + k];
      tile[k] = make_float4(cr.y, cr.z, cr.w, np_norm2(cr.y, cr.z, cr.w));
    }
    __syncthreads();
    for (int j = 0; j < n; j++) {
      float4 c = tile[j];                  // wave-uniform LDS broadcast
      float dd = lattice_d2(qx,qy,qz,n2, c.x,c.y,c.z,c.w);
      if (dd < d3) {                       // rare (harmonic); strict <
        int ci = t + j;
        if (dd < d1) {
          if (dd < d0) { d3=d2v; d2v=d1;i2=i1; d1=d0;i1=i0; d0=dd;i0=ci; }
          else         { d3=d2v; d2v=d1;i2=i1; d1=dd;i1=ci; }
        } else {
          if (dd < d2v){ d3=d2v; d2v=dd;i2=ci; }
          else         { d3=dd; }
        }
      }
    }
  }
  if (valid) {
    size_t base = (size_t)(frame * NP + q) * nseg + seg;
    pd[base] = make_float4(d0, d1, d2v, d3);
    pi[base] = make_int4(i0, i1, i2, -1);
  }
}

// ---------------- Kernel B1b: merge partials -> top-3 + boundary-tie mark ----------------
// A segment's 4th entry can never be global rank<=2 (3 smaller exist in its own
// segment), so its missing index is harmless; boundary ties (bd2==bd3) are
// value-detected and re-resolved exactly.
__global__ void __launch_bounds__(256) knn_merge_kernel(
    const float4* __restrict__ pd, const int4* __restrict__ pi,
    float* __restrict__ wd, int* __restrict__ wi,
    int* __restrict__ mark_cnt, int* __restrict__ mark_rows,
    int RP, int nseg)
{
  int row = blockIdx.x * 256 + threadIdx.x;
  if (row >= RP) return;
  float m0=1e30f, m1=1e30f, m2v=1e30f, m3=1e30f;
  int   j0=0, j1=0, j2=0;
  for (int s = 0; s < nseg; s++) {
    float4 d = pd[(size_t)row * nseg + s];
    int4  ii = pi[(size_t)row * nseg + s];
    float dv[4] = { d.x, d.y, d.z, d.w };
    int   iv[4] = { ii.x, ii.y, ii.z, -1 };
    #pragma unroll
    for (int r = 0; r < 4; r++) {
      float dd = dv[r]; int jj = iv[r];
      if (dd < m3) {
        if (dd < m1) {
          if (dd < m0) { m3=m2v; m2v=m1;j2=j1; m1=m0;j1=j0; m0=dd;j0=jj; }
          else         { m3=m2v; m2v=m1;j2=j1; m1=dd;j1=jj; }
        } else {
          if (dd < m2v){ m3=m2v; m2v=dd;j2=jj; }
          else         { m3=dd; }
        }
      }
    }
  }
  size_t base = (size_t)row * 3;
  wd[base+0]=m0; wd[base+1]=m1; wd[base+2]=m2v;
  wi[base+0]=j0; wi[base+1]=j1; wi[base+2]=j2;
  if (m2v == m3) {
    int slot = atomicAdd(mark_cnt, 1);
    if (slot < MAXMARK) mark_rows[slot] = row;
  }
}

// ---------------- Kernel B1.5: block-PARALLEL exact numpy argsort head (R21, passes) ----------------
__global__ void __launch_bounds__(256) tie_resort_kernel(
    const float4* __restrict__ coords, const float4* __restrict__ pts,
    const int* __restrict__ mark_cnt, const int* __restrict__ mark_rows,
    float* __restrict__ wd, int* __restrict__ wi, int NC, int NP)
{
  __shared__ unsigned short t[NCMAX];
  __shared__ unsigned short Rpos[NCMAX];
  __shared__ unsigned int abit[NWORDS], bbit[NWORDS];
  __shared__ int scanA[256], scanB[256];
  __shared__ int s_pl, s_pr, s_sp, s_state, s_K, s_LK;
  __shared__ float s_vp, s_q[4], vloc[16];
  __shared__ int s_slo[64], s_shi[64];

  int cnt = *mark_cnt; if (cnt > MAXMARK) cnt = MAXMARK;
  int b = blockIdx.x;
  if (b >= cnt) return;
  int row = mark_rows[b];
  int frame = row / NP;
  int q = row - frame * NP;
  int tid = threadIdx.x;

  if (tid == 0) {
    float4 p = pts[(size_t)frame * NP + q];
    s_q[0]=p.y; s_q[1]=p.z; s_q[2]=p.w;
    s_q[3]=np_norm2(p.y,p.z,p.w);
    s_pl = 0; s_pr = NC - 1; s_sp = 0; s_state = 0;
  }
  for (int i = tid; i < NC; i += 256) t[i] = (unsigned short)i;
  __syncthreads();
  float qx=s_q[0], qy=s_q[1], qz=s_q[2], n2=s_q[3];
  const float4* C = coords + (size_t)frame * NC;

  auto V = [&](int p)->float {
    float4 c = C[t[p]];
    float m2 = np_norm2(c.y, c.z, c.w);
    return lattice_d2(qx,qy,qz,n2, c.y,c.z,c.w,m2);
  };

  for (;;) {
    __syncthreads();
    if (s_state) break;
    int pl = s_pl, pr = s_pr;

    if (pr - pl > 15) {
      if (tid == 0) {
        int pm = pl + ((pr - pl) >> 1);
        unsigned short tmp;
        if (V(pm) < V(pl)) { tmp=t[pm]; t[pm]=t[pl]; t[pl]=tmp; }
        if (V(pr) < V(pm)) { tmp=t[pr]; t[pr]=t[pm]; t[pm]=tmp; }
        if (V(pm) < V(pl)) { tmp=t[pm]; t[pm]=t[pl]; t[pl]=tmp; }
        s_vp = V(pm);
        tmp=t[pm]; t[pm]=t[pr-1]; t[pr-1]=tmp;
        s_K = 0;
      }
      __syncthreads();
      float vp = s_vp;
      int M = pr - pl + 1;
      int nwords = (M + 31) >> 5;
      int wpt = (nwords + 255) >> 8;
      int wlo = tid * wpt;
      int whi = min(wlo + wpt, nwords);

      int cA = 0, cB = 0;
      for (int w = wlo; w < whi; ++w) {
        unsigned int wa = 0, wb = 0;
        int rbase = w << 5;
        #pragma unroll 8
        for (int bit = 0; bit < 32; ++bit) {
          int r = rbase + bit;
          bool in = (r < M);
          float val = V(in ? (pl + r) : pl);
          if (in && r >= 1 && r <= M-2 && !(val < vp)) wa |= (1u << bit);
          if (in && r <= M-3 && !(vp < val))           wb |= (1u << bit);
        }
        abit[w] = wa; bbit[w] = wb;
        cA += __popc(wa); cB += __popc(wb);
      }
      scanA[tid] = cA; scanB[tid] = cB;
      __syncthreads();
      for (int off = 1; off < 256; off <<= 1) {
        int aa = (tid >= off) ? scanA[tid-off] : 0;
        int bb = (tid >= off) ? scanB[tid-off] : 0;
        __syncthreads();
        scanA[tid] += aa; scanB[tid] += bb;
        __syncthreads();
      }
      int offA = scanA[tid] - cA;
      int offB = scanB[tid] - cB;
      int nB = scanB[255];
      __syncthreads();

      int run = offB;
      for (int w = wlo; w < whi; ++w) {
        unsigned int wb = bbit[w];
        while (wb) {
          int bit = __ffs(wb) - 1; wb &= wb - 1;
          run++;
          Rpos[nB - run] = (unsigned short)(pl + (w << 5) + bit);
        }
      }
      __syncthreads();

      int k = offA, localK = 0;
      for (int w = wlo; w < whi; ++w) {
        unsigned int wa = abit[w];
        while (wa) {
          int bit = __ffs(wa) - 1; wa &= wa - 1;
          int pos = pl + (w << 5) + bit;
          if (k < nB && pos < (int)Rpos[k]) localK++;
          k++;
        }
      }
      if (localK) atomicAdd(&s_K, localK);
      __syncthreads();
      int K = s_K;

      k = offA;
      for (int w = wlo; w < whi; ++w) {
        unsigned int wa = abit[w];
        while (wa) {
          int bit = __ffs(wa) - 1; wa &= wa - 1;
          int pos = pl + (w << 5) + bit;
          if (k < K) {
            int pp = Rpos[k];
            unsigned short tmp = t[pos]; t[pos] = t[pp]; t[pp] = tmp;
          } else if (k == K) {
            s_LK = pos;
          }
          k++;
        }
      }
      __syncthreads();

      if (tid == 0) {
        int pi2 = s_LK;
        if (K > 0) { int rk = Rpos[K-1]; if (rk < pi2) pi2 = rk; }
        unsigned short tmp = t[pi2]; t[pi2] = t[pr-1]; t[pr-1] = tmp;
        if (pi2 - pl < pr - pi2) {
          if (pi2 + 1 <= 3) { s_slo[s_sp] = pi2 + 1; s_shi[s_sp] = pr; s_sp++; }
          s_pr = pi2 - 1;
        } else {
          s_slo[s_sp] = pl; s_shi[s_sp] = pi2 - 1; s_sp++;
          s_pl = pi2 + 1;
          if (s_pl > 3) {
            --s_sp; s_pl = s_slo[s_sp]; s_pr = s_shi[s_sp];
          }
        }
      }
    } else {
      if (pr > pl && tid <= pr - pl) vloc[tid] = V(pl + tid);
      __syncthreads();
      if (tid == 0) {
        for (int a2 = pl + 1; a2 <= pr; ++a2) {
          unsigned short vi = t[a2]; float vv = vloc[a2 - pl];
          int b2 = a2;
          while (b2 > pl && vv < vloc[b2-1-pl]) {
            t[b2] = t[b2-1]; vloc[b2-pl] = vloc[b2-1-pl]; --b2;
          }
          t[b2] = vi; vloc[b2-pl] = vv;
        }
        if (s_sp == 0) s_state = 1;
        else { --s_sp; s_pl = s_slo[s_sp]; s_pr = s_shi[s_sp]; }
      }
    }
  }

  __syncthreads();
  if (tid == 0) {
    size_t base = (size_t)row * 3;
    wd[base+0]=V(0); wd[base+1]=V(1); wd[base+2]=V(2);
    wi[base+0]=t[0]; wi[base+1]=t[1]; wi[base+2]=t[2];
  }
}

// ---------------- Kernel B2: np-f32 weights + interpolate + align + out head ----------------
__global__ void __launch_bounds__(64) interp_mlp_kernel(
    const float* __restrict__ feats,
    const float* __restrict__ wd, const int* __restrict__ wi,
    const float* __restrict__ al_w, const float* __restrict__ al_b,
    const float* __restrict__ al_g, const float* __restrict__ al_bb,
    const float* __restrict__ al_m, const float* __restrict__ al_v,
    const float* __restrict__ o_w1,
    const float* __restrict__ o_g, const float* __restrict__ o_bb,
    const float* __restrict__ o_m, const float* __restrict__ o_v,
    const float* __restrict__ o_w2, const float* __restrict__ o_b2,
    float* __restrict__ out, int NC, int NP, int B)
{
  __shared__ float s1[HID], t1[HID], s2[HID], t2[HID];
  int tx = threadIdx.x;
  if (tx < HID) {
    float sa = al_g[tx] / sqrtf(al_v[tx] + EPS_AL);
    s1[tx] = sa;
    t1[tx] = (al_b[tx] - al_m[tx]) * sa + al_bb[tx];
    float so = o_g[tx] / sqrtf(o_v[tx] + EPS_CLS);
    s2[tx] = so;
    t2[tx] = o_bb[tx] - o_m[tx] * so;
  }
  __syncthreads();
  int r = blockIdx.x * 64 + tx;
  if (r >= B * NP) return;
  int frame = r / NP;

  float bd0 = wd[(size_t)r*3+0], bd1 = wd[(size_t)r*3+1], bd2 = wd[(size_t)r*3+2];
  int   bi0 = wi[(size_t)r*3+0], bi1 = wi[(size_t)r*3+1], bi2 = wi[(size_t)r*3+2];

  float w0 = pin(__fdiv_rn(1.0f, addrn_b(fmaxf(bd0, 0.f), 1e-8f)));
  float w1 = pin(__fdiv_rn(1.0f, addrn_b(fmaxf(bd1, 0.f), 1e-8f)));
  float w2 = pin(__fdiv_rn(1.0f, addrn_b(fmaxf(bd2, 0.f), 1e-8f)));
  float wsum = addrn_b(addrn_b(w0, w1), w2);
  w0 = pin(__fdiv_rn(w0, wsum)); w1 = pin(__fdiv_rn(w1, wsum)); w2 = pin(__fdiv_rn(w2, wsum));

  const float* F = feats + (size_t)frame * NC * HID;
  const float4* F0 = (const float4*)(F + (size_t)bi0 * HID);
  const float4* F1 = (const float4*)(F + (size_t)bi1 * HID);
  const float4* F2 = (const float4*)(F + (size_t)bi2 * HID);

  float interp[HID];
  #pragma unroll
  for (int i = 0; i < 16; i++) {
    float4 a = F0[i], b = F1[i], c = F2[i];
    interp[4*i+0] = (a.x*w0 + b.x*w1) + c.x*w2;
    interp[4*i+1] = (a.y*w0 + b.y*w1) + c.y*w2;
    interp[4*i+2] = (a.z*w0 + b.z*w1) + c.z*w2;
    interp[4*i+3] = (a.w*w0 + b.w*w1) + c.w*w2;
  }

  float f[HID];
  #pragma unroll
  for (int j = 0; j < HID; j++) {
    float acc = 0.f;
    #pragma unroll
    for (int k = 0; k < HID; k++) acc = fmaf(interp[k], al_w[k*HID + j], acc);
    f[j] = relu_(acc * s1[j] + t1[j]);
  }
  float o[NCLS];
  #pragma unroll
  for (int c = 0; c < NCLS; c++) o[c] = o_b2[c];
  #pragma unroll
  for (int j = 0; j < HID; j++) {
    float acc = 0.f;
    #pragma unroll
    for (int k = 0; k < HID; k++) acc = fmaf(f[k], o_w1[k*HID + j], acc);
    float h = relu_(acc * s2[j] + t2[j]);
    #pragma unroll
    for (int c = 0; c < NCLS; c++) o[c] = fmaf(h, o_w2[j*NCLS + c], o[c]);
  }
  float4* op = (float4*)(out + (size_t)r * NCLS);
  #pragma unroll
  for (int i = 0; i < 5; i++) op[i] = make_float4(o[4*i], o[4*i+1], o[4*i+2], o[4*i+3]);
}

extern "C" void kernel_launch(void* const* d_in, const int* in_sizes, int n_in,
                              void* d_out, int out_size, void* d_ws, size_t ws_size,
                              hipStream_t stream)
{
  const float*  feats  = (const float*) d_in[0];
  const float4* coords = (const float4*)d_in[1];
  const float4* pts    = (const float4*)d_in[2];
  const float* cls_w1 = (const float*)d_in[3];
  const float* cls_g  = (const float*)d_in[4];
  const float* cls_b  = (const float*)d_in[5];
  const float* cls_m  = (const float*)d_in[6];
  const float* cls_v  = (const float*)d_in[7];
  const float* cls_w2 = (const float*)d_in[8];
  const float* cls_b2 = (const float*)d_in[9];
  const float* al_w   = (const float*)d_in[10];
  const float* al_b   = (const float*)d_in[11];
  const float* al_g   = (const float*)d_in[12];
  const float* al_bb  = (const float*)d_in[13];
  const float* al_m   = (const float*)d_in[14];
  const float* al_v   = (const float*)d_in[15];
  const float* o_w1   = (const float*)d_in[16];
  const float* o_g    = (const float*)d_in[17];
  const float* o_bb   = (const float*)d_in[18];
  const float* o_m    = (const float*)d_in[19];
  const float* o_v    = (const float*)d_in[20];
  const float* o_w2   = (const float*)d_in[21];
  const float* o_b2   = (const float*)d_in[22];

  const int B = 2;
  int RC = in_sizes[1] / 4;  int NC = RC / B;
  int RP = in_sizes[2] / 4;  int NP = RP / B;

  // nseg chosen to fit workspace: 1KB header + wd/wi (RP*3*4 each) + pd/pi (RP*nseg*16 each)
  int nseg = NSEG;
  while (nseg > 1 &&
         1024 + (size_t)RP*3*8 + (size_t)RP*nseg*32 > ws_size) nseg >>= 1;

  int*   mark_cnt  = (int*)d_ws;
  int*   mark_rows = (int*)((char*)d_ws + 16);
  float* wd  = (float*)((char*)d_ws + 1024);
  int*   wi  = (int*)((char*)wd + (size_t)RP * 3 * 4);
  float4* pd = (float4*)((char*)wi + (size_t)RP * 3 * 4);
  int4*   pi = (int4*)((char*)pd + (size_t)RP * nseg * 16);

  hipMemsetAsync(d_ws, 0, 16, stream);

  cls_head_kernel<<<(RC + 63) / 64, 64, 0, stream>>>(
      feats, cls_w1, cls_g, cls_b, cls_m, cls_v, cls_w2, cls_b2,
      (float*)d_out, RC);

  dim3 g1((NP + 255) / 256, nseg, B);
  knn_scan_kernel<<<g1, 256, 0, stream>>>(coords, pts, pd, pi, NC, NP, nseg);

  knn_merge_kernel<<<(RP + 255) / 256, 256, 0, stream>>>(
      pd, pi, wd, wi, mark_cnt, mark_rows, RP, nseg);

  tie_resort_kernel<<<MAXMARK, 256, 0, stream>>>(coords, pts, mark_cnt, mark_rows,
                                                 wd, wi, NC, NP);

  float* out2 = (float*)d_out + (size_t)RC * NCLS;
  interp_mlp_kernel<<<(RP + 63) / 64, 64, 0, stream>>>(
      feats, wd, wi,
      al_w, al_b, al_g, al_bb, al_m, al_v,
      o_w1, o_g, o_bb, o_m, o_v, o_w2, o_b2,
      out2, NC, NP, B);
}